// Round 2
// baseline (1868.193 us; speedup 1.0000x reference)
//
#include <hip/hip_runtime.h>

#define DIM 2048
#define INTER 1408
#define NE 15
#define T_TOKENS 4096
#define NROUTED (T_TOKENS * 2)      // 8192 routed slots
#define NSLOT (NROUTED + T_TOKENS)  // + 4096 shared = 12288

using short8 = __attribute__((ext_vector_type(8))) short;
using f32x4  = __attribute__((ext_vector_type(4))) float;

__device__ __forceinline__ unsigned short f2bf(float f) {
    return (unsigned short)((__float_as_uint(f) + 0x8000u) >> 16);
}
__device__ __forceinline__ unsigned pk2bf(unsigned a, unsigned b) {
    // pack two fp32 bit patterns -> two bf16 (round-half-up), one v_perm
    return __builtin_amdgcn_perm(b + 0x8000u, a + 0x8000u, 0x07060302u);
}
__device__ __forceinline__ uint4 cvt8(float4 f0, float4 f1) {
    uint4 r;
    r.x = pk2bf(__float_as_uint(f0.x), __float_as_uint(f0.y));
    r.y = pk2bf(__float_as_uint(f0.z), __float_as_uint(f0.w));
    r.z = pk2bf(__float_as_uint(f1.x), __float_as_uint(f1.y));
    r.w = pk2bf(__float_as_uint(f1.z), __float_as_uint(f1.w));
    return r;
}
__device__ __forceinline__ float bl(unsigned u) { return __uint_as_float(u << 16); }
__device__ __forceinline__ float bh(unsigned u) { return __uint_as_float(u & 0xffff0000u); }

// async global -> LDS, 16B per lane; lds dest = wave-uniform base + lane*16
__device__ __forceinline__ void async_cp16(const unsigned short* g, unsigned short* l) {
    __builtin_amdgcn_global_load_lds(
        (const __attribute__((address_space(1))) unsigned int*)g,
        (__attribute__((address_space(3))) unsigned int*)l,
        16, 0, 0);
}

// ---------------- fp32 -> bf16, 8 elems/thread ----------------
__global__ void cvt8_kernel(const float* __restrict__ src, unsigned short* __restrict__ dst) {
    size_t i = ((size_t)blockIdx.x * 256 + threadIdx.x) * 8;
    float4 a = *(const float4*)(src + i);
    float4 b = *(const float4*)(src + i + 4);
    *(uint4*)(dst + i) = cvt8(a, b);
}

// ---------------- gating: softmax over 15, top-2 ----------------
__global__ void gate_kernel(const float* __restrict__ x, const float* __restrict__ gw,
                            int* __restrict__ tk_idx, float* __restrict__ tk_w,
                            int* __restrict__ cnt) {
    int tok = blockIdx.x;
    int lane = threadIdx.x; // 64 threads
    const float* xr = x + (size_t)tok * DIM;
    float s[NE];
#pragma unroll
    for (int e = 0; e < NE; e++) s[e] = 0.f;
    for (int k = lane; k < DIM; k += 64) {
        float xv = xr[k];
#pragma unroll
        for (int e = 0; e < NE; e++) s[e] += xv * gw[e * DIM + k];
    }
#pragma unroll
    for (int e = 0; e < NE; e++) {
#pragma unroll
        for (int off = 32; off >= 1; off >>= 1) s[e] += __shfl_xor(s[e], off, 64);
    }
    if (lane == 0) {
        float mx = s[0];
#pragma unroll
        for (int e = 1; e < NE; e++) mx = fmaxf(mx, s[e]);
        float p[NE]; float den = 0.f;
#pragma unroll
        for (int e = 0; e < NE; e++) { p[e] = __expf(s[e] - mx); den += p[e]; }
        float inv = 1.f / den;
        int i0 = 0, i1 = -1; float b0 = p[0], b1 = -1.f;
#pragma unroll
        for (int e = 1; e < NE; e++) {
            float v = p[e];
            if (v > b0) { b1 = b0; i1 = i0; b0 = v; i0 = e; }
            else if (v > b1) { b1 = v; i1 = e; }
        }
        tk_idx[tok * 2] = i0;     tk_idx[tok * 2 + 1] = i1;
        tk_w[tok * 2] = b0 * inv; tk_w[tok * 2 + 1] = b1 * inv;
        atomicAdd(&cnt[i0], 1);   atomicAdd(&cnt[i1], 1);
    }
}

// ---------------- prefix offsets (16 segments incl. shared) ----------------
__global__ void offsets_kernel(int* __restrict__ cnt, int* __restrict__ off) {
    if (threadIdx.x == 0 && blockIdx.x == 0) {
        int a = 0;
        for (int e = 0; e < NE; e++) { off[e] = a; a += cnt[e]; }
        off[NE] = NROUTED;      // shared segment starts at 8192
        cnt[NE] = T_TOKENS;     // shared expert gets every token
    }
}

// ---------------- scatter tokens into slots ----------------
__global__ void scatter_kernel(const int* __restrict__ tk_idx,
                               const int* __restrict__ off, int* __restrict__ fill,
                               int* __restrict__ rows, int* __restrict__ inv) {
    int id = blockIdx.x * 256 + threadIdx.x;
    if (id < NROUTED) {
        int e = tk_idx[id];
        int pos = off[e] + atomicAdd(&fill[e], 1);
        rows[pos] = id >> 1;
        inv[id] = pos;
    } else if (id < NSLOT) {
        rows[id] = id - NROUTED;
    }
}

// ---------------- GEMM1: Ha = silu(X w1^T) * (X w3^T), fused, bf16 weights ----------------
// grid (32 m-tiles, 11 n-tiles, 16 experts) — m fastest so neighbors share weight tiles in L2
__global__ __launch_bounds__(256, 2)
void gemm1_kernel(const unsigned short* __restrict__ xb,
                  const unsigned short* __restrict__ wb1,
                  const unsigned short* __restrict__ wb3,
                  const int* __restrict__ rows, const int* __restrict__ off,
                  const int* __restrict__ cnt,
                  unsigned short* __restrict__ Ha) {
    __shared__ unsigned short As[128 * 32];
    __shared__ unsigned short B1s[128 * 32];
    __shared__ unsigned short B3s[128 * 32];
    __shared__ int rowLds[128];

    const int e = blockIdx.z;
    const int count = cnt[e];
    const int m0 = blockIdx.x * 128;
    if (m0 >= count) return;
    const int base = off[e];
    const int n0 = blockIdx.y * 128;

    const unsigned short* W1 = wb1 + (size_t)e * INTER * DIM + (size_t)n0 * DIM;
    const unsigned short* W3 = wb3 + (size_t)e * INTER * DIM + (size_t)n0 * DIM;

    const int tid = threadIdx.x;
    if (tid < 128) {
        int mi = m0 + tid;
        rowLds[tid] = rows[base + ((mi < count) ? mi : 0)];
    }
    __syncthreads();

    const int wave = tid >> 6, lane = tid & 63;
    const int sr = lane >> 2, seg = lane & 3;
    const int r0 = wave * 32 + sr;        // staging rows for this wave
    const int r1 = wave * 32 + 16 + sr;

    const unsigned short* gA0 = xb + (size_t)rowLds[r0] * DIM + seg * 8;
    const unsigned short* gA1 = xb + (size_t)rowLds[r1] * DIM + seg * 8;
    const unsigned short* gB10 = W1 + (size_t)r0 * DIM + seg * 8;
    const unsigned short* gB11 = W1 + (size_t)r1 * DIM + seg * 8;
    const unsigned short* gB30 = W3 + (size_t)r0 * DIM + seg * 8;
    const unsigned short* gB31 = W3 + (size_t)r1 * DIM + seg * 8;

    unsigned short* lA0 = As + (size_t)(wave * 32) * 32;
    unsigned short* lA1 = As + (size_t)(wave * 32 + 16) * 32;
    unsigned short* lB10 = B1s + (size_t)(wave * 32) * 32;
    unsigned short* lB11 = B1s + (size_t)(wave * 32 + 16) * 32;
    unsigned short* lB30 = B3s + (size_t)(wave * 32) * 32;
    unsigned short* lB31 = B3s + (size_t)(wave * 32 + 16) * 32;

    const int wm = (wave >> 1) * 64, wn = (wave & 1) * 64;
    const int lr = lane & 15, lq = lane >> 4;
    const unsigned short* afp  = As  + (wm + lr) * 32 + lq * 8;
    const unsigned short* b1fp = B1s + (wn + lr) * 32 + lq * 8;
    const unsigned short* b3fp = B3s + (wn + lr) * 32 + lq * 8;

    f32x4 acc1[16], acc3[16];
    const f32x4 fz = {0.f, 0.f, 0.f, 0.f};
#pragma unroll
    for (int i = 0; i < 16; i++) { acc1[i] = fz; acc3[i] = fz; }

    for (int kt = 0; kt < DIM / 32; ++kt) {
        async_cp16(gA0, lA0);   async_cp16(gA1, lA1);
        async_cp16(gB10, lB10); async_cp16(gB11, lB11);
        async_cp16(gB30, lB30); async_cp16(gB31, lB31);
        gA0 += 32; gA1 += 32; gB10 += 32; gB11 += 32; gB30 += 32; gB31 += 32;
        __syncthreads();
        short8 af[4], b1f[4], b3f[4];
#pragma unroll
        for (int i = 0; i < 4; i++) af[i] = *(const short8*)(afp + i * 16 * 32);
#pragma unroll
        for (int j = 0; j < 4; j++) {
            b1f[j] = *(const short8*)(b1fp + j * 16 * 32);
            b3f[j] = *(const short8*)(b3fp + j * 16 * 32);
        }
#pragma unroll
        for (int i = 0; i < 4; i++)
#pragma unroll
            for (int j = 0; j < 4; j++) {
                acc1[i * 4 + j] = __builtin_amdgcn_mfma_f32_16x16x32_bf16(af[i], b1f[j], acc1[i * 4 + j], 0, 0, 0);
                acc3[i * 4 + j] = __builtin_amdgcn_mfma_f32_16x16x32_bf16(af[i], b3f[j], acc3[i * 4 + j], 0, 0, 0);
            }
        __syncthreads();
    }

    // fused SiLU epilogue -> Ha (bf16)
#pragma unroll
    for (int i = 0; i < 4; i++) {
#pragma unroll
        for (int t = 0; t < 4; t++) {
            int lm = wm + i * 16 + lq * 4 + t;
            int mi = m0 + lm;
            if (mi < count) {
                size_t rowbase = (size_t)(base + mi) * INTER + n0 + wn + lr;
#pragma unroll
                for (int j = 0; j < 4; j++) {
                    float h1 = acc1[i * 4 + j][t];
                    float h3 = acc3[i * 4 + j][t];
                    float hv = h1 / (1.f + __expf(-h1)) * h3;
                    Ha[rowbase + j * 16] = f2bf(hv);
                }
            }
        }
    }
}

// ---------------- GEMM2: Hout[slot] = Ha[slot] @ w2^T (unscaled), bf16 ----------------
// grid (32 m-tiles, 16 n-tiles, 16 experts)
__global__ __launch_bounds__(256, 2)
void gemm2_kernel(const unsigned short* __restrict__ Ha,
                  const unsigned short* __restrict__ wb2,
                  const int* __restrict__ off, const int* __restrict__ cnt,
                  unsigned short* __restrict__ Hout) {
    __shared__ unsigned short As[128 * 32];
    __shared__ unsigned short Bs[128 * 32];

    const int e = blockIdx.z;
    const int count = cnt[e];
    const int m0 = blockIdx.x * 128;
    if (m0 >= count) return;
    const int base = off[e];
    const int s0 = base + m0;
    const int n0 = blockIdx.y * 128;

    const unsigned short* W2 = wb2 + (size_t)e * DIM * INTER + (size_t)n0 * INTER;

    const int tid = threadIdx.x;
    const int wave = tid >> 6, lane = tid & 63;
    const int sr = lane >> 2, seg = lane & 3;
    const int r0 = wave * 32 + sr;
    const int r1 = wave * 32 + 16 + sr;

    const unsigned short* gA0 = Ha + (size_t)(s0 + r0) * INTER + seg * 8;
    const unsigned short* gA1 = Ha + (size_t)(s0 + r1) * INTER + seg * 8;
    const unsigned short* gB0 = W2 + (size_t)r0 * INTER + seg * 8;
    const unsigned short* gB1 = W2 + (size_t)r1 * INTER + seg * 8;

    unsigned short* lA0 = As + (size_t)(wave * 32) * 32;
    unsigned short* lA1 = As + (size_t)(wave * 32 + 16) * 32;
    unsigned short* lB0 = Bs + (size_t)(wave * 32) * 32;
    unsigned short* lB1 = Bs + (size_t)(wave * 32 + 16) * 32;

    const int wm = (wave >> 1) * 64, wn = (wave & 1) * 64;
    const int lr = lane & 15, lq = lane >> 4;
    const unsigned short* afp = As + (wm + lr) * 32 + lq * 8;
    const unsigned short* bfp = Bs + (wn + lr) * 32 + lq * 8;

    f32x4 acc[16];
    const f32x4 fz = {0.f, 0.f, 0.f, 0.f};
#pragma unroll
    for (int i = 0; i < 16; i++) acc[i] = fz;

    for (int kt = 0; kt < INTER / 32; ++kt) {
        async_cp16(gA0, lA0); async_cp16(gA1, lA1);
        async_cp16(gB0, lB0); async_cp16(gB1, lB1);
        gA0 += 32; gA1 += 32; gB0 += 32; gB1 += 32;
        __syncthreads();
        short8 af[4], bf_[4];
#pragma unroll
        for (int i = 0; i < 4; i++) af[i] = *(const short8*)(afp + i * 16 * 32);
#pragma unroll
        for (int j = 0; j < 4; j++) bf_[j] = *(const short8*)(bfp + j * 16 * 32);
#pragma unroll
        for (int i = 0; i < 4; i++)
#pragma unroll
            for (int j = 0; j < 4; j++)
                acc[i * 4 + j] = __builtin_amdgcn_mfma_f32_16x16x32_bf16(af[i], bf_[j], acc[i * 4 + j], 0, 0, 0);
        __syncthreads();
    }

#pragma unroll
    for (int i = 0; i < 4; i++) {
#pragma unroll
        for (int t = 0; t < 4; t++) {
            int lm = wm + i * 16 + lq * 4 + t;
            int mi = m0 + lm;
            if (mi < count) {
                size_t rowbase = (size_t)(s0 + lm) * DIM + n0 + wn + lr;
#pragma unroll
                for (int j = 0; j < 4; j++)
                    Hout[rowbase + j * 16] = f2bf(acc[i * 4 + j][t]);
            }
        }
    }
}

// ---------------- combine: out[t] = wA*Hout[sA] + wB*Hout[sB] + Hout[shared] ----------------
__global__ void combine_kernel(const unsigned short* __restrict__ Hout,
                               const int* __restrict__ inv,
                               const float* __restrict__ tk_w,
                               float* __restrict__ out) {
    int t = blockIdx.x;
    int c = threadIdx.x * 8;
    int sA = inv[t * 2], sB = inv[t * 2 + 1];
    float wA = tk_w[t * 2], wB = tk_w[t * 2 + 1];
    uint4 a = *(const uint4*)(Hout + (size_t)sA * DIM + c);
    uint4 b = *(const uint4*)(Hout + (size_t)sB * DIM + c);
    uint4 s = *(const uint4*)(Hout + (size_t)(NROUTED + t) * DIM + c);
    float4 o0, o1;
    o0.x = wA * bl(a.x) + wB * bl(b.x) + bl(s.x);
    o0.y = wA * bh(a.x) + wB * bh(b.x) + bh(s.x);
    o0.z = wA * bl(a.y) + wB * bl(b.y) + bl(s.y);
    o0.w = wA * bh(a.y) + wB * bh(b.y) + bh(s.y);
    o1.x = wA * bl(a.z) + wB * bl(b.z) + bl(s.z);
    o1.y = wA * bh(a.z) + wB * bh(b.z) + bh(s.z);
    o1.z = wA * bl(a.w) + wB * bl(b.w) + bl(s.w);
    o1.w = wA * bh(a.w) + wB * bh(b.w) + bh(s.w);
    float* orow = out + (size_t)t * DIM + c;
    *(float4*)orow = o0;
    *(float4*)(orow + 4) = o1;
}

extern "C" void kernel_launch(void* const* d_in, const int* in_sizes, int n_in,
                              void* d_out, int out_size, void* d_ws, size_t ws_size,
                              hipStream_t stream) {
    const float* x   = (const float*)d_in[0];
    const float* gw  = (const float*)d_in[1];
    const float* w1  = (const float*)d_in[2];
    const float* w3  = (const float*)d_in[3];
    const float* w2  = (const float*)d_in[4];
    const float* sw1 = (const float*)d_in[5];
    const float* sw3 = (const float*)d_in[6];
    const float* sw2 = (const float*)d_in[7];
    float* out = (float*)d_out;

    char* p = (char*)d_ws;
    unsigned short* xb  = (unsigned short*)p; p += (size_t)T_TOKENS * DIM * 2;    // 16.8 MB
    unsigned short* Ha  = (unsigned short*)p; p += (size_t)NSLOT * INTER * 2;     // 34.6 MB
    unsigned short* wb1 = (unsigned short*)p; p += (size_t)16 * INTER * DIM * 2;  // 92.3 MB
    unsigned short* wb3 = (unsigned short*)p; p += (size_t)16 * INTER * DIM * 2;  // 92.3 MB
    unsigned short* wb2 = (unsigned short*)p; p += (size_t)16 * DIM * INTER * 2;  // 92.3 MB
    int*   rows   = (int*)p;   p += NSLOT * 4;
    int*   inv    = (int*)p;   p += NROUTED * 4;
    int*   tk_idx = (int*)p;   p += NROUTED * 4;
    float* tk_w   = (float*)p; p += NROUTED * 4;
    int*   cnt    = (int*)p;   p += 64;
    int*   fill   = (int*)p;   p += 64;
    int*   off    = (int*)p;   p += 64;
    // Hout aliases wb1 (wb1 is dead after gemm1; Hout needs 50.3 MB <= 92.3 MB)
    unsigned short* Hout = wb1;

    hipMemsetAsync(cnt, 0, 192, stream);  // cnt + fill + off

    cvt8_kernel<<<(T_TOKENS * DIM) / 2048, 256, 0, stream>>>(x, xb);
    cvt8_kernel<<<(NE * INTER * DIM) / 2048, 256, 0, stream>>>(w1, wb1);
    cvt8_kernel<<<(INTER * DIM) / 2048, 256, 0, stream>>>(sw1, wb1 + (size_t)NE * INTER * DIM);
    cvt8_kernel<<<(NE * INTER * DIM) / 2048, 256, 0, stream>>>(w3, wb3);
    cvt8_kernel<<<(INTER * DIM) / 2048, 256, 0, stream>>>(sw3, wb3 + (size_t)NE * INTER * DIM);
    cvt8_kernel<<<(NE * DIM * INTER) / 2048, 256, 0, stream>>>(w2, wb2);
    cvt8_kernel<<<(DIM * INTER) / 2048, 256, 0, stream>>>(sw2, wb2 + (size_t)NE * DIM * INTER);

    gate_kernel<<<T_TOKENS, 64, 0, stream>>>(x, gw, tk_idx, tk_w, cnt);
    offsets_kernel<<<1, 64, 0, stream>>>(cnt, off);
    scatter_kernel<<<NSLOT / 256, 256, 0, stream>>>(tk_idx, off, fill, rows, inv);

    gemm1_kernel<<<dim3(32, 11, 16), 256, 0, stream>>>(xb, wb1, wb3, rows, off, cnt, Ha);
    gemm2_kernel<<<dim3(32, 16, 16), 256, 0, stream>>>(Ha, wb2, off, cnt, Hout);
    combine_kernel<<<T_TOKENS, 256, 0, stream>>>(Hout, inv, tk_w, out);
}